// Round 5
// baseline (129.025 us; speedup 1.0000x reference)
//
#include <hip/hip_runtime.h>
#include <hip/hip_bf16.h>
#include <stdint.h>

// SketchConv2d: out = conv2d(x, Weff) + bias, where
// Weff[o,f] = (1/4) * sum_{n,s} sketches[n,f,s] * signed[n,s,o]
// f channel-major flat (c*9 + kh*3 + kw).
//
// B=32, CIN=128, H=W=64, OUT=256, KH=KW=3, H2=W2=62, NSK=4, SDIM=128.
//
// Round 5: r4 structure + T3/T4 counted-vmcnt pipeline (guide §5.5).
//  - raw s_barrier + manual `s_waitcnt vmcnt(4)` (never 0 in steady state):
//    A-stage for step s+2 issued right after step s's reads complete, so
//    every stage has ~2 steps of flight time. No __syncthreads drain.
//  - 2 barriers/step (data-ready, write-after-read), setprio(1) on MFMA.

#define BATCH 32
#define CIN   128
#define HH    64
#define WW    64
#define OUTC  256
#define H2    62
#define W2    62
#define A_TILE 32768                  // 256 o x 64 k x 2B per step
#define WS_A_BYTES (18 * A_TILE)
#define BKHB  17408                   // 68 j-rows * 256 B per x-row

typedef __bf16 bf16x8 __attribute__((ext_vector_type(8)));
typedef float  f32x4  __attribute__((ext_vector_type(4)));

typedef unsigned int u32_as1 __attribute__((address_space(1)));
typedef unsigned int u32_as3 __attribute__((address_space(3)));

__device__ __forceinline__ void async_copy16(const void* g, void* l) {
  __builtin_amdgcn_global_load_lds((const u32_as1*)g, (u32_as3*)l, 16, 0, 0);
}

// ---------------------------------------------------------------------------
// Kernel 1: Weff -> 18 pre-swizzled LDS tile images in ws (unchanged).
// image byte: s*32768 + o*128 + ((kk*2) ^ ((o&7)<<4)),  kk = c & 63,
// s = (kh*3+kw)*2 + (c>>6).
// ---------------------------------------------------------------------------
#define FPB 4
__global__ __launch_bounds__(256) void weff_kernel(
    const float* __restrict__ sketches,   // (4, 1152, 128)
    const float* __restrict__ sgn,        // (4, 128, 256)
    char* __restrict__ wsA)
{
  __shared__ alignas(16) float sk[512 * FPB];
  const int f0 = blockIdx.x * FPB;
  const int t  = threadIdx.x;

  for (int k = 0; k < (512 * FPB) / 256; ++k) {
    int idx = t + k * 256;
    int fi  = idx >> 9;
    int ns  = idx & 511;
    int n   = ns >> 7;
    int s   = ns & 127;
    sk[ns * FPB + fi] = sketches[(n * 1152 + f0 + fi) * 128 + s];
  }
  __syncthreads();

  const int o = t;
  float acc0 = 0.f, acc1 = 0.f, acc2 = 0.f, acc3 = 0.f;
#pragma unroll 8
  for (int ns = 0; ns < 512; ++ns) {
    float sg = sgn[ns * 256 + o];
    f32x4 skv = *(const f32x4*)(&sk[ns * FPB]);
    acc0 += sg * skv[0];
    acc1 += sg * skv[1];
    acc2 += sg * skv[2];
    acc3 += sg * skv[3];
  }

  float accs[FPB] = {acc0, acc1, acc2, acc3};
#pragma unroll
  for (int fi = 0; fi < FPB; ++fi) {
    int f    = f0 + fi;
    int c    = f / 9;
    int khkw = f - c * 9;
    int s    = khkw * 2 + (c >> 6);
    int kk   = c & 63;
    uint32_t byteoff = (uint32_t)s * A_TILE + (uint32_t)o * 128
                     + (((uint32_t)kk * 2u) ^ (uint32_t)((o & 7) << 4));
    *(__hip_bfloat16*)(wsA + byteoff) = __float2bfloat16(accs[fi] * 0.25f);
  }
}

// ---------------------------------------------------------------------------
// Kernel 2: implicit-GEMM conv, counted-vmcnt double-buffered A pipeline.
// Block (b, i-pair): 256 o x 64 j x 2 i-rows, 8 waves (512 thr).
// ---------------------------------------------------------------------------
__global__ __launch_bounds__(512, 2) void conv_kernel(
    const float* __restrict__ x,
    const char*  __restrict__ wA,
    const float* __restrict__ bias,
    float* __restrict__ out)
{
  __shared__ alignas(16) char lds[65536 + 4 * BKHB];   // 64 KB A-dbuf + 68 KB B
  char* ldsA = lds;
  char* ldsB = lds + 65536;

  const int bid = blockIdx.x;
  const int swz = (bid & 7) * 124 + (bid >> 3);   // 992 = 8*124, bijective
  const int b   = swz / 31;
  const int ip  = swz - b * 31;
  const int i0  = ip * 2;

  const int t    = threadIdx.x;
  const int lane = t & 63;
  const int w    = t >> 6;       // 0..7
  const int wo   = w >> 1;       // o-quarter
  const int ir   = w & 1;        // i-row of the pair

#define STAGE_A(LIN, BUF) do {                                             \
    const char* asrc_ = wA + (size_t)(LIN) * A_TILE + w * 1024 + lane * 16;\
    char* adst_ = ldsA + (BUF) * 32768 + w * 1024;                         \
    async_copy16(asrc_,          adst_);                                   \
    async_copy16(asrc_ + 8192,   adst_ + 8192);                            \
    async_copy16(asrc_ + 16384,  adst_ + 16384);                           \
    async_copy16(asrc_ + 24576,  adst_ + 24576);                           \
  } while (0)

  // prologue: both A buffers in flight
  STAGE_A(0, 0);
  STAGE_A(1, 1);

  // ---- stage B once: x[b, :, i0..i0+3, :] -> bf16 LDS [r][j][c], swizzled
  {
    const int j  = t & 63;
    const int cq = t >> 6;                         // 8 groups of 16 channels
    const uint32_t swb = (uint32_t)((j & 7) << 4);
#pragma unroll
    for (int r = 0; r < 4; ++r) {
      const float* xr = x + (((size_t)(b * CIN + cq * 16)) * HH + (i0 + r)) * WW + j;
      char* lrow = ldsB + r * BKHB + j * 256;
#pragma unroll
      for (int g = 0; g < 2; ++g) {
        bf16x8 pk;
#pragma unroll
        for (int cc = 0; cc < 8; ++cc)
          pk[cc] = (__bf16)xr[(size_t)(g * 8 + cc) * (HH * WW)];
        uint32_t c0b = (uint32_t)(cq * 32 + g * 16);
        *(bf16x8*)(lrow + (c0b ^ swb)) = pk;
      }
    }
    // zero the 4 pad j-rows (64..67) of each x-row
    if (t < 256) {
      int r  = t >> 6;
      int pj = 64 + ((t >> 4) & 3);
      int sl = (t & 15) * 16;
      bf16x8 z = {};
      *(bf16x8*)(ldsB + r * BKHB + pj * 256 + sl) = z;
    }
  }

  f32x4 acc[4][4];
  const f32x4 zf = {0.f, 0.f, 0.f, 0.f};
#pragma unroll
  for (int mi = 0; mi < 4; ++mi)
#pragma unroll
    for (int ni = 0; ni < 4; ++ni)
      acc[mi][ni] = zf;

  // ---- per-lane LDS read bases
  const int ln15  = lane & 15;
  const int khi16 = (lane >> 4) << 4;
  const uint32_t swa = (uint32_t)((ln15 & 7) << 4);
  const char* pAr = ldsA + (wo * 64 + ln15) * 128;
  const char* pA0 = pAr + (((uint32_t)khi16) ^ swa);          // ks=0
  const char* pA1 = pAr + (((uint32_t)(64 | khi16)) ^ swa);   // ks=1

#define MKB(KW, KS) (ldsB + ir * BKHB + (ln15 + (KW)) * 256                \
    + (((uint32_t)(((KS) << 6) | khi16)) ^ ((uint32_t)(((ln15 + (KW)) & 7) << 4))))
  const char* pB00 = MKB(0, 0); const char* pB01 = MKB(0, 1);
  const char* pB10 = MKB(1, 0); const char* pB11 = MKB(1, 1);
  const char* pB20 = MKB(2, 0); const char* pB21 = MKB(2, 1);
#undef MKB

  // wave's own B ds_writes must be complete before first barrier
  asm volatile("s_waitcnt lgkmcnt(0)" ::: "memory");

#define MFMA_ __builtin_amdgcn_mfma_f32_16x16x32_bf16
#define WAITVM4 asm volatile("s_waitcnt vmcnt(4)" ::: "memory")
#define WAITVM0 asm volatile("s_waitcnt vmcnt(0)" ::: "memory")
#define WAITLG0 asm volatile("s_waitcnt lgkmcnt(0)" ::: "memory")

  // one K-step: counted-vmcnt wait, barrier, 16 ds_reads, WAR barrier,
  // issue stage(s+2) into freed buffer, 32 MFMA under setprio(1).
#define STEP(LIN, KH, KW, WVM) do {                                        \
    WVM;                                                                   \
    __builtin_amdgcn_s_barrier();                                          \
    const int ai_  = ((LIN) & 1) * 32768;                                  \
    const int chb_ = ((LIN) & 1) * 128 + (KH) * BKHB;                      \
    bf16x8 aA0 = *(const bf16x8*)(pA0 + ai_);                              \
    bf16x8 aA1 = *(const bf16x8*)(pA0 + ai_ + 2048);                       \
    bf16x8 aA2 = *(const bf16x8*)(pA0 + ai_ + 4096);                       \
    bf16x8 aA3 = *(const bf16x8*)(pA0 + ai_ + 6144);                       \
    bf16x8 aB0 = *(const bf16x8*)(pA1 + ai_);                              \
    bf16x8 aB1 = *(const bf16x8*)(pA1 + ai_ + 2048);                       \
    bf16x8 aB2 = *(const bf16x8*)(pA1 + ai_ + 4096);                       \
    bf16x8 aB3 = *(const bf16x8*)(pA1 + ai_ + 6144);                       \
    bf16x8 bA0 = *(const bf16x8*)(pB##KW##0 + chb_);                       \
    bf16x8 bA1 = *(const bf16x8*)(pB##KW##0 + chb_ + 4096);                \
    bf16x8 bA2 = *(const bf16x8*)(pB##KW##0 + chb_ + 8192);                \
    bf16x8 bA3 = *(const bf16x8*)(pB##KW##0 + chb_ + 12288);               \
    bf16x8 bB0 = *(const bf16x8*)(pB##KW##1 + chb_);                       \
    bf16x8 bB1 = *(const bf16x8*)(pB##KW##1 + chb_ + 4096);                \
    bf16x8 bB2 = *(const bf16x8*)(pB##KW##1 + chb_ + 8192);                \
    bf16x8 bB3 = *(const bf16x8*)(pB##KW##1 + chb_ + 12288);               \
    WAITLG0;                                                               \
    __builtin_amdgcn_sched_barrier(0);                                     \
    __builtin_amdgcn_s_barrier();                                          \
    if ((LIN) < 16) STAGE_A((LIN) + 2, (LIN) & 1);                         \
    __builtin_amdgcn_s_setprio(1);                                         \
    acc[0][0] = MFMA_(aA0, bA0, acc[0][0], 0, 0, 0);                       \
    acc[0][1] = MFMA_(aA0, bA1, acc[0][1], 0, 0, 0);                       \
    acc[0][2] = MFMA_(aA0, bA2, acc[0][2], 0, 0, 0);                       \
    acc[0][3] = MFMA_(aA0, bA3, acc[0][3], 0, 0, 0);                       \
    acc[1][0] = MFMA_(aA1, bA0, acc[1][0], 0, 0, 0);                       \
    acc[1][1] = MFMA_(aA1, bA1, acc[1][1], 0, 0, 0);                       \
    acc[1][2] = MFMA_(aA1, bA2, acc[1][2], 0, 0, 0);                       \
    acc[1][3] = MFMA_(aA1, bA3, acc[1][3], 0, 0, 0);                       \
    acc[2][0] = MFMA_(aA2, bA0, acc[2][0], 0, 0, 0);                       \
    acc[2][1] = MFMA_(aA2, bA1, acc[2][1], 0, 0, 0);                       \
    acc[2][2] = MFMA_(aA2, bA2, acc[2][2], 0, 0, 0);                       \
    acc[2][3] = MFMA_(aA2, bA3, acc[2][3], 0, 0, 0);                       \
    acc[3][0] = MFMA_(aA3, bA0, acc[3][0], 0, 0, 0);                       \
    acc[3][1] = MFMA_(aA3, bA1, acc[3][1], 0, 0, 0);                       \
    acc[3][2] = MFMA_(aA3, bA2, acc[3][2], 0, 0, 0);                       \
    acc[3][3] = MFMA_(aA3, bA3, acc[3][3], 0, 0, 0);                       \
    acc[0][0] = MFMA_(aB0, bB0, acc[0][0], 0, 0, 0);                       \
    acc[0][1] = MFMA_(aB0, bB1, acc[0][1], 0, 0, 0);                       \
    acc[0][2] = MFMA_(aB0, bB2, acc[0][2], 0, 0, 0);                       \
    acc[0][3] = MFMA_(aB0, bB3, acc[0][3], 0, 0, 0);                       \
    acc[1][0] = MFMA_(aB1, bB0, acc[1][0], 0, 0, 0);                       \
    acc[1][1] = MFMA_(aB1, bB1, acc[1][1], 0, 0, 0);                       \
    acc[1][2] = MFMA_(aB1, bB2, acc[1][2], 0, 0, 0);                       \
    acc[1][3] = MFMA_(aB1, bB3, acc[1][3], 0, 0, 0);                       \
    acc[2][0] = MFMA_(aB2, bB0, acc[2][0], 0, 0, 0);                       \
    acc[2][1] = MFMA_(aB2, bB1, acc[2][1], 0, 0, 0);                       \
    acc[2][2] = MFMA_(aB2, bB2, acc[2][2], 0, 0, 0);                       \
    acc[2][3] = MFMA_(aB2, bB3, acc[2][3], 0, 0, 0);                       \
    acc[3][0] = MFMA_(aB3, bB0, acc[3][0], 0, 0, 0);                       \
    acc[3][1] = MFMA_(aB3, bB1, acc[3][1], 0, 0, 0);                       \
    acc[3][2] = MFMA_(aB3, bB2, acc[3][2], 0, 0, 0);                       \
    acc[3][3] = MFMA_(aB3, bB3, acc[3][3], 0, 0, 0);                       \
    __builtin_amdgcn_s_setprio(0);                                         \
  } while (0)

  STEP(0, 0, 0, WAITVM4);   STEP(1, 0, 0, WAITVM4);
  STEP(2, 0, 1, WAITVM4);   STEP(3, 0, 1, WAITVM4);
  STEP(4, 0, 2, WAITVM4);   STEP(5, 0, 2, WAITVM4);
  STEP(6, 1, 0, WAITVM4);   STEP(7, 1, 0, WAITVM4);
  STEP(8, 1, 1, WAITVM4);   STEP(9, 1, 1, WAITVM4);
  STEP(10, 1, 2, WAITVM4);  STEP(11, 1, 2, WAITVM4);
  STEP(12, 2, 0, WAITVM4);  STEP(13, 2, 0, WAITVM4);
  STEP(14, 2, 1, WAITVM4);  STEP(15, 2, 1, WAITVM4);
  STEP(16, 2, 2, WAITVM4);  STEP(17, 2, 2, WAITVM0);

#undef STEP
#undef WAITLG0
#undef WAITVM0
#undef WAITVM4
#undef MFMA_
#undef STAGE_A

  // ---- epilogue: D[m][n]: m=(lane>>4)*4+reg, n=lane&15
  const int jn   = ln15;
  const int g4   = lane >> 4;
  const int irow = i0 + ir;
#pragma unroll
  for (int mi = 0; mi < 4; ++mi) {
#pragma unroll
    for (int ni = 0; ni < 4; ++ni) {
      const int jj = (ni << 4) + jn;
      if (jj < W2) {
#pragma unroll
        for (int rr = 0; rr < 4; ++rr) {
          const int o = (wo << 6) + (mi << 4) + (g4 << 2) + rr;
          out[(((size_t)b * OUTC + o) * H2 + irow) * W2 + jj] = acc[mi][ni][rr] + bias[o];
        }
      }
    }
  }
}

extern "C" void kernel_launch(void* const* d_in, const int* in_sizes, int n_in,
                              void* d_out, int out_size, void* d_ws, size_t ws_size,
                              hipStream_t stream) {
  const float* x        = (const float*)d_in[0];
  const float* sketches = (const float*)d_in[1];
  const float* sgn      = (const float*)d_in[2];
  const float* bias     = (const float*)d_in[3];
  float* out            = (float*)d_out;
  char* wsA             = (char*)d_ws;

  if (ws_size < (size_t)WS_A_BYTES) return;  // need 576 KB scratch

  weff_kernel<<<1152 / FPB, 256, 0, stream>>>(sketches, sgn, wsA);
  conv_kernel<<<BATCH * (H2 / 2), 512, 0, stream>>>(x, wsA, bias, out);
}

// Round 7
// 106.547 us; speedup vs baseline: 1.2110x; 1.2110x over previous
//
#include <hip/hip_runtime.h>
#include <hip/hip_bf16.h>
#include <stdint.h>

// SketchConv2d: out = conv2d(x, Weff) + bias, where
// Weff[o,f] = (1/4) * sum_{n,s} sketches[n,f,s] * signed[n,s,o]
// f channel-major flat (c*9 + kh*3 + kw).
//
// B=32, CIN=128, H=W=64, OUT=256, KH=KW=3, H2=W2=62, NSK=4, SDIM=128.
//
// Round 7: r4-proven schedule (stage-at-top, __syncthreads-at-end: the
// catalog's minimum-2-phase; r6's post-barrier vmcnt was a cross-wave race),
// with 2x bigger tile to amortize the per-step overhead:
//   block = 256 o x 256 e (4 i-rows x 64 j), 8 waves, wave = 128 o x 64 e.
//   A: 32 KB/step dbuf via global_load_lds (pre-swizzled image in ws).
//   B: 6 x-rows staged ONCE as bf16 [6][64 j][256 B] swizzled (96 KB).
//   LDS = 64 + 96 = 160 KB. Grid = 32 b x 16 i-groups = 512 blocks.

#define BATCH 32
#define CIN   128
#define HH    64
#define WW    64
#define OUTC  256
#define H2    62
#define W2    62
#define A_TILE 32768                  // 256 o x 64 k x 2B per step
#define WS_A_BYTES (18 * A_TILE)
#define BROWB 16384                   // 64 j * 256 B per x-row

typedef __bf16 bf16x8 __attribute__((ext_vector_type(8)));
typedef float  f32x4  __attribute__((ext_vector_type(4)));

typedef unsigned int u32_as1 __attribute__((address_space(1)));
typedef unsigned int u32_as3 __attribute__((address_space(3)));

__device__ __forceinline__ void async_copy16(const void* g, void* l) {
  __builtin_amdgcn_global_load_lds((const u32_as1*)g, (u32_as3*)l, 16, 0, 0);
}

// ---------------------------------------------------------------------------
// Kernel 1: Weff -> 18 pre-swizzled LDS tile images in ws (unchanged).
// image byte: s*32768 + o*128 + ((kk*2) ^ ((o&7)<<4)),  kk = c & 63,
// s = (kh*3+kw)*2 + (c>>6).
// ---------------------------------------------------------------------------
#define FPB 4
__global__ __launch_bounds__(256) void weff_kernel(
    const float* __restrict__ sketches,   // (4, 1152, 128)
    const float* __restrict__ sgn,        // (4, 128, 256)
    char* __restrict__ wsA)
{
  __shared__ alignas(16) float sk[512 * FPB];
  const int f0 = blockIdx.x * FPB;
  const int t  = threadIdx.x;

  for (int k = 0; k < (512 * FPB) / 256; ++k) {
    int idx = t + k * 256;
    int fi  = idx >> 9;
    int ns  = idx & 511;
    int n   = ns >> 7;
    int s   = ns & 127;
    sk[ns * FPB + fi] = sketches[(n * 1152 + f0 + fi) * 128 + s];
  }
  __syncthreads();

  const int o = t;
  float acc0 = 0.f, acc1 = 0.f, acc2 = 0.f, acc3 = 0.f;
#pragma unroll 8
  for (int ns = 0; ns < 512; ++ns) {
    float sg = sgn[ns * 256 + o];
    f32x4 skv = *(const f32x4*)(&sk[ns * FPB]);
    acc0 += sg * skv[0];
    acc1 += sg * skv[1];
    acc2 += sg * skv[2];
    acc3 += sg * skv[3];
  }

  float accs[FPB] = {acc0, acc1, acc2, acc3};
#pragma unroll
  for (int fi = 0; fi < FPB; ++fi) {
    int f    = f0 + fi;
    int c    = f / 9;
    int khkw = f - c * 9;
    int s    = khkw * 2 + (c >> 6);
    int kk   = c & 63;
    uint32_t byteoff = (uint32_t)s * A_TILE + (uint32_t)o * 128
                     + (((uint32_t)kk * 2u) ^ (uint32_t)((o & 7) << 4));
    *(__hip_bfloat16*)(wsA + byteoff) = __float2bfloat16(accs[fi] * 0.25f);
  }
}

// ---------------------------------------------------------------------------
// Kernel 2: implicit-GEMM conv, 256o x 256e block, 2-phase pipelined K-loop.
// 8 waves: wo = w>>2 (o-half of 128), we = w&3 (i-row). 512 threads.
// ---------------------------------------------------------------------------
__global__ __launch_bounds__(512, 2) void conv_kernel(
    const float* __restrict__ x,
    const char*  __restrict__ wA,
    const float* __restrict__ bias,
    float* __restrict__ out)
{
  __shared__ alignas(16) char lds[65536 + 6 * BROWB];  // 64 KB A-dbuf + 96 KB B
  char* ldsA = lds;
  char* ldsB = lds + 65536;

  const int bid = blockIdx.x;
  const int swz = (bid & 7) * 64 + (bid >> 3);    // 512 = 8*64, bijective
  const int b   = swz >> 4;
  const int ig  = swz & 15;
  const int i0  = ig * 4;

  const int t    = threadIdx.x;
  const int lane = t & 63;
  const int w    = t >> 6;       // 0..7
  const int wo   = w >> 2;       // o-half (128 o's)
  const int we   = w & 3;        // i-row within group

#define STAGE_A(LIN, BUF) do {                                             \
    const char* asrc_ = wA + (size_t)(LIN) * A_TILE + w * 1024 + lane * 16;\
    char* adst_ = ldsA + (BUF) * 32768 + w * 1024;                         \
    async_copy16(asrc_,          adst_);                                   \
    async_copy16(asrc_ + 8192,   adst_ + 8192);                            \
    async_copy16(asrc_ + 16384,  adst_ + 16384);                           \
    async_copy16(asrc_ + 24576,  adst_ + 24576);                           \
  } while (0)

  STAGE_A(0, 0);   // in flight across the whole B staging

  // ---- stage B once: x[b, :, i0..i0+5 (clamped), :] -> [r][j][c] bf16, swz
  {
    const int j  = t & 63;
    const int cq = t >> 6;                         // 8 groups of 16 channels
    const uint32_t swb = (uint32_t)((j & 7) << 4);
#pragma unroll
    for (int r = 0; r < 6; ++r) {
      int xrow = i0 + r; if (xrow > 63) xrow = 63;
      const float* xr = x + (((size_t)(b * CIN + cq * 16)) * HH + xrow) * WW + j;
      char* lrow = ldsB + r * BROWB + j * 256;
#pragma unroll
      for (int g = 0; g < 2; ++g) {
        bf16x8 pk;
#pragma unroll
        for (int cc = 0; cc < 8; ++cc)
          pk[cc] = (__bf16)xr[(size_t)(g * 8 + cc) * (HH * WW)];
        uint32_t c0b = (uint32_t)(cq * 32 + g * 16);
        *(bf16x8*)(lrow + (c0b ^ swb)) = pk;
      }
    }
  }

  f32x4 acc[8][4];
  const f32x4 zf = {0.f, 0.f, 0.f, 0.f};
#pragma unroll
  for (int mi = 0; mi < 8; ++mi)
#pragma unroll
    for (int ni = 0; ni < 4; ++ni)
      acc[mi][ni] = zf;

  // ---- per-lane LDS read bases
  const int ln15  = lane & 15;
  const int khi16 = (lane >> 4) << 4;
  const uint32_t swa = (uint32_t)((ln15 & 7) << 4);
  const char* pAr = ldsA + (wo * 128 + ln15) * 128;
  const char* pA0 = pAr + (((uint32_t)khi16) ^ swa);          // ks=0
  const char* pA1 = pAr + (((uint32_t)(64 | khi16)) ^ swa);   // ks=1

  // B bases: ni<3 use pB + ni*4096 (col&7 invariant under +16);
  // ni=3 needs col clamp (col = 48+ln15+kw may exceed 63) -> pC.
#define MKB(COL, KS) (ldsB + (we * 64 + (COL)) * 256                       \
    + (((uint32_t)(((KS) << 6) | khi16)) ^ ((uint32_t)(((COL) & 7) << 4))))
  const char* pB00 = MKB(ln15 + 0, 0); const char* pB01 = MKB(ln15 + 0, 1);
  const char* pB10 = MKB(ln15 + 1, 0); const char* pB11 = MKB(ln15 + 1, 1);
  const char* pB20 = MKB(ln15 + 2, 0); const char* pB21 = MKB(ln15 + 2, 1);
  const int c30 = (48 + ln15 + 0 > 63) ? 63 : 48 + ln15 + 0;
  const int c31 = (48 + ln15 + 1 > 63) ? 63 : 48 + ln15 + 1;
  const int c32 = (48 + ln15 + 2 > 63) ? 63 : 48 + ln15 + 2;
  const char* pC00 = MKB(c30, 0); const char* pC01 = MKB(c30, 1);
  const char* pC10 = MKB(c31, 0); const char* pC11 = MKB(c31, 1);
  const char* pC20 = MKB(c32, 0); const char* pC21 = MKB(c32, 1);
#undef MKB

  __syncthreads();   // drains STAGE_A(0) (vmcnt0) + B ds_writes (lgkm0)

#define MFMA_ __builtin_amdgcn_mfma_f32_16x16x32_bf16

  // one ks half: 8 A reads + 4 B reads + 32 MFMA
#define KSH(AP, BP, CP, IMM, AIMM) do {                                    \
    bf16x8 b0_ = *(const bf16x8*)((BP) + (IMM));                           \
    bf16x8 b1_ = *(const bf16x8*)((BP) + (IMM) + 4096);                    \
    bf16x8 b2_ = *(const bf16x8*)((BP) + (IMM) + 8192);                    \
    bf16x8 b3_ = *(const bf16x8*)((CP) + (IMM));                           \
    bf16x8 a0_ = *(const bf16x8*)((AP) + (AIMM));                          \
    bf16x8 a1_ = *(const bf16x8*)((AP) + (AIMM) + 2048);                   \
    bf16x8 a2_ = *(const bf16x8*)((AP) + (AIMM) + 4096);                   \
    bf16x8 a3_ = *(const bf16x8*)((AP) + (AIMM) + 6144);                   \
    bf16x8 a4_ = *(const bf16x8*)((AP) + (AIMM) + 8192);                   \
    bf16x8 a5_ = *(const bf16x8*)((AP) + (AIMM) + 10240);                  \
    bf16x8 a6_ = *(const bf16x8*)((AP) + (AIMM) + 12288);                  \
    bf16x8 a7_ = *(const bf16x8*)((AP) + (AIMM) + 14336);                  \
    acc[0][0] = MFMA_(a0_, b0_, acc[0][0], 0, 0, 0);                       \
    acc[0][1] = MFMA_(a0_, b1_, acc[0][1], 0, 0, 0);                       \
    acc[0][2] = MFMA_(a0_, b2_, acc[0][2], 0, 0, 0);                       \
    acc[0][3] = MFMA_(a0_, b3_, acc[0][3], 0, 0, 0);                       \
    acc[1][0] = MFMA_(a1_, b0_, acc[1][0], 0, 0, 0);                       \
    acc[1][1] = MFMA_(a1_, b1_, acc[1][1], 0, 0, 0);                       \
    acc[1][2] = MFMA_(a1_, b2_, acc[1][2], 0, 0, 0);                       \
    acc[1][3] = MFMA_(a1_, b3_, acc[1][3], 0, 0, 0);                       \
    acc[2][0] = MFMA_(a2_, b0_, acc[2][0], 0, 0, 0);                       \
    acc[2][1] = MFMA_(a2_, b1_, acc[2][1], 0, 0, 0);                       \
    acc[2][2] = MFMA_(a2_, b2_, acc[2][2], 0, 0, 0);                       \
    acc[2][3] = MFMA_(a2_, b3_, acc[2][3], 0, 0, 0);                       \
    acc[3][0] = MFMA_(a3_, b0_, acc[3][0], 0, 0, 0);                       \
    acc[3][1] = MFMA_(a3_, b1_, acc[3][1], 0, 0, 0);                       \
    acc[3][2] = MFMA_(a3_, b2_, acc[3][2], 0, 0, 0);                       \
    acc[3][3] = MFMA_(a3_, b3_, acc[3][3], 0, 0, 0);                       \
    acc[4][0] = MFMA_(a4_, b0_, acc[4][0], 0, 0, 0);                       \
    acc[4][1] = MFMA_(a4_, b1_, acc[4][1], 0, 0, 0);                       \
    acc[4][2] = MFMA_(a4_, b2_, acc[4][2], 0, 0, 0);                       \
    acc[4][3] = MFMA_(a4_, b3_, acc[4][3], 0, 0, 0);                       \
    acc[5][0] = MFMA_(a5_, b0_, acc[5][0], 0, 0, 0);                       \
    acc[5][1] = MFMA_(a5_, b1_, acc[5][1], 0, 0, 0);                       \
    acc[5][2] = MFMA_(a5_, b2_, acc[5][2], 0, 0, 0);                       \
    acc[5][3] = MFMA_(a5_, b3_, acc[5][3], 0, 0, 0);                       \
    acc[6][0] = MFMA_(a6_, b0_, acc[6][0], 0, 0, 0);                       \
    acc[6][1] = MFMA_(a6_, b1_, acc[6][1], 0, 0, 0);                       \
    acc[6][2] = MFMA_(a6_, b2_, acc[6][2], 0, 0, 0);                       \
    acc[6][3] = MFMA_(a6_, b3_, acc[6][3], 0, 0, 0);                       \
    acc[7][0] = MFMA_(a7_, b0_, acc[7][0], 0, 0, 0);                       \
    acc[7][1] = MFMA_(a7_, b1_, acc[7][1], 0, 0, 0);                       \
    acc[7][2] = MFMA_(a7_, b2_, acc[7][2], 0, 0, 0);                       \
    acc[7][3] = MFMA_(a7_, b3_, acc[7][3], 0, 0, 0);                       \
  } while (0)

  // one K-step: stage(s+1) at top (full step of flight), reads+MFMA,
  // __syncthreads at end (vmcnt0+lgkm0+barrier: publish + WAR, r4-proven).
#define STEP(LIN, KH, KW) do {                                             \
    if ((LIN) < 17) STAGE_A((LIN) + 1, ((LIN) + 1) & 1);                   \
    KSH(pA0, pB##KW##0, pC##KW##0,                                         \
        (KH) * BROWB + ((LIN) & 1) * 128, ((LIN) & 1) * 32768);            \
    KSH(pA1, pB##KW##1, pC##KW##1,                                         \
        (KH) * BROWB + ((LIN) & 1) * 128, ((LIN) & 1) * 32768);            \
    if ((LIN) < 17) __syncthreads();                                       \
  } while (0)

  STEP(0, 0, 0);   STEP(1, 0, 0);
  STEP(2, 0, 1);   STEP(3, 0, 1);
  STEP(4, 0, 2);   STEP(5, 0, 2);
  STEP(6, 1, 0);   STEP(7, 1, 0);
  STEP(8, 1, 1);   STEP(9, 1, 1);
  STEP(10, 1, 2);  STEP(11, 1, 2);
  STEP(12, 2, 0);  STEP(13, 2, 0);
  STEP(14, 2, 1);  STEP(15, 2, 1);
  STEP(16, 2, 2);  STEP(17, 2, 2);

#undef STEP
#undef KSH
#undef MFMA_
#undef STAGE_A

  // ---- epilogue: D[m][n]: m=(lane>>4)*4+reg, n=lane&15
  const int jn   = ln15;
  const int g4   = lane >> 4;
  const int irow = i0 + we;
  if (irow < H2) {
#pragma unroll
    for (int mi = 0; mi < 8; ++mi) {
#pragma unroll
      for (int ni = 0; ni < 4; ++ni) {
        const int jj = (ni << 4) + jn;
        if (jj < W2) {
#pragma unroll
          for (int rr = 0; rr < 4; ++rr) {
            const int o = (wo << 7) + (mi << 4) + (g4 << 2) + rr;
            out[(((size_t)b * OUTC + o) * H2 + irow) * W2 + jj] =
                acc[mi][ni][rr] + bias[o];
          }
        }
      }
    }
  }
}

extern "C" void kernel_launch(void* const* d_in, const int* in_sizes, int n_in,
                              void* d_out, int out_size, void* d_ws, size_t ws_size,
                              hipStream_t stream) {
  const float* x        = (const float*)d_in[0];
  const float* sketches = (const float*)d_in[1];
  const float* sgn      = (const float*)d_in[2];
  const float* bias     = (const float*)d_in[3];
  float* out            = (float*)d_out;
  char* wsA             = (char*)d_ws;

  if (ws_size < (size_t)WS_A_BYTES) return;  // need 576 KB scratch

  weff_kernel<<<1152 / FPB, 256, 0, stream>>>(sketches, sgn, wsA);
  conv_kernel<<<BATCH * 16, 512, 0, stream>>>(x, wsA, bias, out);
}